// Round 1
// baseline (3052.548 us; speedup 1.0000x reference)
//
#include <hip/hip_runtime.h>

#define BG 8
#define NP 4096
#define MC 2048
#define KN 64
#define FI 64

// Exact-rounding squared distance matching JAX/np f32 semantics:
// ((dx*dx + dy*dy) + dz*dz), no FMA contraction.
__device__ __forceinline__ float dist2(float ax, float ay, float az,
                                       float bx, float by, float bz) {
    float dx = __fsub_rn(ax, bx), dy = __fsub_rn(ay, by), dz = __fsub_rn(az, bz);
    return __fadd_rn(__fadd_rn(__fmul_rn(dx, dx), __fmul_rn(dy, dy)), __fmul_rn(dz, dz));
}

// ---------------- Kernel 1: FPS (blocks 0..7) + y = x@W1x + b1 (blocks 8..519) -------------
__global__ __launch_bounds__(256) void k1_fps_y(
    const float* __restrict__ pos, const float* __restrict__ x,
    const float* __restrict__ w1, const float* __restrict__ b1,
    float* __restrict__ y, int* __restrict__ cidx,
    float* __restrict__ out_pos, float* __restrict__ out_batch)
{
    __shared__ float smem[12304];
    const int tid = threadIdx.x;
    if (blockIdx.x < BG) {
        // -------- FPS for graph b --------
        const int b = blockIdx.x;
        const float* pg = pos + (size_t)b * NP * 3;
        for (int i = tid; i < NP * 3; i += 256) smem[i] = pg[i];
        __syncthreads();
        float px[16], py[16], pz[16], mind[16];
        const int base = tid * 16;
        #pragma unroll
        for (int i = 0; i < 16; i++) {
            px[i] = smem[(base + i) * 3];
            py[i] = smem[(base + i) * 3 + 1];
            pz[i] = smem[(base + i) * 3 + 2];
            mind[i] = 1e30f;
        }
        float cx = smem[0], cy = smem[1], cz = smem[2];
        if (tid == 0) {
            cidx[b * MC] = 0;
            out_pos[(size_t)b * MC * 3 + 0] = cx;
            out_pos[(size_t)b * MC * 3 + 1] = cy;
            out_pos[(size_t)b * MC * 3 + 2] = cz;
            out_batch[b * MC] = (float)b;
        }
        float* swv = smem + 12288;   // 4 x (val, idx)
        float* sbest = smem + 12296; // x,y,z,idx
        const int lane = tid & 63, wv = tid >> 6;
        for (int m = 1; m < MC; m++) {
            float bv = -1.0f; int bi = 0;
            #pragma unroll
            for (int i = 0; i < 16; i++) {
                float d = dist2(px[i], py[i], pz[i], cx, cy, cz);
                float nm = fminf(mind[i], d);
                mind[i] = nm;
                if (nm > bv) { bv = nm; bi = base + i; }  // ascending i -> first max
            }
            #pragma unroll
            for (int off = 32; off; off >>= 1) {
                float ov = __shfl_down(bv, off, 64);
                int oi = __shfl_down(bi, off, 64);
                if (ov > bv || (ov == bv && oi < bi)) { bv = ov; bi = oi; }
            }
            if (lane == 0) { swv[wv * 2] = bv; swv[wv * 2 + 1] = __int_as_float(bi); }
            __syncthreads();
            if (tid == 0) {
                float v = swv[0]; int ix = __float_as_int(swv[1]);
                for (int w = 1; w < 4; w++) {
                    float ov = swv[w * 2]; int oi = __float_as_int(swv[w * 2 + 1]);
                    if (ov > v || (ov == v && oi < ix)) { v = ov; ix = oi; }
                }
                float nx = smem[ix * 3], ny = smem[ix * 3 + 1], nz = smem[ix * 3 + 2];
                sbest[0] = nx; sbest[1] = ny; sbest[2] = nz; sbest[3] = __int_as_float(ix);
                int ci = b * MC + m;
                cidx[ci] = ix;
                out_pos[(size_t)ci * 3] = nx;
                out_pos[(size_t)ci * 3 + 1] = ny;
                out_pos[(size_t)ci * 3 + 2] = nz;
                out_batch[ci] = (float)b;
            }
            __syncthreads();
            cx = sbest[0]; cy = sbest[1]; cz = sbest[2];
        }
    } else {
        // -------- y = x @ W1x + b1 (64 points per block) --------
        const int q = blockIdx.x - BG;   // 0..511
        const int p0 = q * 64;
        float* xs = smem;                 // 64 x 65 (padded)
        float* wsm = smem + 4160;         // 64 x 64
        float* bsm = smem + 8256;         // 64
        for (int i = tid; i < 4096; i += 256) {
            xs[(i >> 6) * 65 + (i & 63)] = x[(size_t)p0 * 64 + i];
            wsm[i] = w1[i];               // first 64 rows of w1 = x-part
        }
        if (tid < 64) bsm[tid] = b1[tid];
        __syncthreads();
        const int pl = tid >> 2, oq = tid & 3;
        float acc[16];
        #pragma unroll
        for (int u = 0; u < 16; u++) acc[u] = bsm[oq * 16 + u];
        for (int f = 0; f < 64; f++) {
            float xv = xs[pl * 65 + f];
            const float4* wp = (const float4*)&wsm[f * 64 + oq * 16];
            float4 a = wp[0], b4 = wp[1], c4 = wp[2], d4 = wp[3];
            acc[0] = fmaf(xv, a.x, acc[0]);   acc[1] = fmaf(xv, a.y, acc[1]);
            acc[2] = fmaf(xv, a.z, acc[2]);   acc[3] = fmaf(xv, a.w, acc[3]);
            acc[4] = fmaf(xv, b4.x, acc[4]);  acc[5] = fmaf(xv, b4.y, acc[5]);
            acc[6] = fmaf(xv, b4.z, acc[6]);  acc[7] = fmaf(xv, b4.w, acc[7]);
            acc[8] = fmaf(xv, c4.x, acc[8]);  acc[9] = fmaf(xv, c4.y, acc[9]);
            acc[10] = fmaf(xv, c4.z, acc[10]); acc[11] = fmaf(xv, c4.w, acc[11]);
            acc[12] = fmaf(xv, d4.x, acc[12]); acc[13] = fmaf(xv, d4.y, acc[13]);
            acc[14] = fmaf(xv, d4.z, acc[14]); acc[15] = fmaf(xv, d4.w, acc[15]);
        }
        float4* yo = (float4*)&y[((size_t)p0 + pl) * 64 + oq * 16];
        yo[0] = make_float4(acc[0], acc[1], acc[2], acc[3]);
        yo[1] = make_float4(acc[4], acc[5], acc[6], acc[7]);
        yo[2] = make_float4(acc[8], acc[9], acc[10], acc[11]);
        yo[3] = make_float4(acc[12], acc[13], acc[14], acc[15]);
    }
}

// ---------------- Kernel 2: radius-capped kNN per center -------------
__global__ __launch_bounds__(256) void k2_nbr(
    const float* __restrict__ pos, const int* __restrict__ cidx,
    int* __restrict__ nbr, int* __restrict__ cntg)
{
    __shared__ float smem[12288 + 4 * 480 * 2];
    const int tid = threadIdx.x, lane = tid & 63, wv = tid >> 6;
    const int b = blockIdx.x >> 5, blk = blockIdx.x & 31;
    const float* pg = pos + (size_t)b * NP * 3;
    for (int i = tid; i < NP * 3; i += 256) smem[i] = pg[i];
    __syncthreads();
    float2* cb = (float2*)(smem + 12288) + wv * 480;
    const int wi = blk * 4 + wv;    // 0..127
    for (int t = 0; t < 16; t++) {
        const int m = wi + 128 * t, ci = b * MC + m;
        const int cj = cidx[ci];
        const float cx = smem[cj * 3], cy = smem[cj * 3 + 1], cz = smem[cj * 3 + 2];
        int cnt = 0;
        for (int c = 0; c < 64; c++) {
            const int p = c * 64 + lane;
            float d2 = dist2(smem[p * 3], smem[p * 3 + 1], smem[p * 3 + 2], cx, cy, cz);
            bool inr = d2 <= 0.25f;
            unsigned long long mk = __ballot(inr);
            int pre = __popcll(mk & ((1ull << lane) - 1ull));
            int wp = cnt + pre;
            if (inr && wp < 480) cb[wp] = make_float2(d2, __int_as_float(p));
            cnt += __popcll(mk);
        }
        if (cnt > 480) cnt = 480;
        if (cnt <= KN) {
            if (lane < cnt) { float2 e = cb[lane]; nbr[(size_t)ci * KN + lane] = __float_as_int(e.y); }
            if (lane == 0) cntg[ci] = cnt;
        } else {
            for (int basej = 0; basej < cnt; basej += 64) {
                int jj = basej + lane;
                float dj = 3.4e38f; int ij = 0x7fffffff;
                bool act = jj < cnt;
                if (act) { float2 e = cb[jj]; dj = e.x; ij = __float_as_int(e.y); }
                int rank = 0;
                for (int l = 0; l < cnt; l++) {
                    float2 e = cb[l];
                    float dl = e.x; int il = __float_as_int(e.y);
                    if (dl < dj || (dl == dj && il < ij)) rank++;
                }
                if (act && rank < KN) nbr[(size_t)ci * KN + rank] = ij;
            }
            if (lane == 0) cntg[ci] = KN;
        }
    }
}

// ---------------- Kernel 3: per-center MLP + masked max -------------
__global__ __launch_bounds__(256, 2) void k3_mlp(
    const float* __restrict__ y, const float* __restrict__ pos,
    const int* __restrict__ nbr, const int* __restrict__ cntg,
    const float* __restrict__ w1, const float* __restrict__ w2, const float* __restrict__ b2,
    const float* __restrict__ w3, const float* __restrict__ b3,
    const float* __restrict__ out_pos, float* __restrict__ out_x)
{
    __shared__ float smem[4 * 136];
    const int tid = threadIdx.x, o = tid & 63, wv = tid >> 6;
    float w2c[64], w3a[64], w3b[64];
    #pragma unroll
    for (int f = 0; f < 64; f++) {
        w2c[f] = w2[f * 64 + o];
        w3a[f] = w3[f * 128 + o];
        w3b[f] = w3[f * 128 + 64 + o];
    }
    const float b2v = b2[o], b3av = b3[o], b3bv = b3[o + 64];
    const float wp0 = w1[64 * 64 + o], wp1 = w1[65 * 64 + o], wp2 = w1[66 * 64 + o];
    float* st1 = smem + wv * 136;
    float* st2 = st1 + 68;
    const int gw = blockIdx.x * 4 + wv;   // 0..4095
    for (int t = 0; t < 4; t++) {
        const int ci = gw + 4096 * t;
        const int b = ci >> 11;           // / MC
        const int kc = cntg[ci];
        const float cx = out_pos[(size_t)ci * 3], cy = out_pos[(size_t)ci * 3 + 1], cz = out_pos[(size_t)ci * 3 + 2];
        float mA = -3.4e38f, mB = -3.4e38f;
        for (int k = 0; k < kc; k++) {
            const int j = nbr[(size_t)ci * KN + k];
            const size_t pj = (size_t)b * NP + j;
            float yv = y[pj * 64 + o];
            float jx = pos[pj * 3], jy = pos[pj * 3 + 1], jz = pos[pj * 3 + 2];
            float rx = jx - cx, ry = jy - cy, rz = jz - cz;
            float h1 = fmaf(rx, wp0, yv);
            h1 = fmaf(ry, wp1, h1);
            h1 = fmaf(rz, wp2, h1);
            h1 = fmaxf(h1, 0.f);
            st1[o] = h1;
            float a2 = b2v;
            #pragma unroll
            for (int fc = 0; fc < 16; fc++) {
                float4 h = *(const float4*)&st1[fc * 4];
                a2 = fmaf(h.x, w2c[fc * 4], a2);
                a2 = fmaf(h.y, w2c[fc * 4 + 1], a2);
                a2 = fmaf(h.z, w2c[fc * 4 + 2], a2);
                a2 = fmaf(h.w, w2c[fc * 4 + 3], a2);
            }
            float h2 = fmaxf(a2, 0.f);
            st2[o] = h2;
            float a3 = b3av, a4 = b3bv;
            #pragma unroll
            for (int fc = 0; fc < 16; fc++) {
                float4 h = *(const float4*)&st2[fc * 4];
                a3 = fmaf(h.x, w3a[fc * 4], a3);
                a3 = fmaf(h.y, w3a[fc * 4 + 1], a3);
                a3 = fmaf(h.z, w3a[fc * 4 + 2], a3);
                a3 = fmaf(h.w, w3a[fc * 4 + 3], a3);
                a4 = fmaf(h.x, w3b[fc * 4], a4);
                a4 = fmaf(h.y, w3b[fc * 4 + 1], a4);
                a4 = fmaf(h.z, w3b[fc * 4 + 2], a4);
                a4 = fmaf(h.w, w3b[fc * 4 + 3], a4);
            }
            mA = fmaxf(mA, a3);
            mB = fmaxf(mB, a4);
        }
        out_x[(size_t)ci * 128 + o] = mA;
        out_x[(size_t)ci * 128 + 64 + o] = mB;
    }
}

extern "C" void kernel_launch(void* const* d_in, const int* in_sizes, int n_in,
                              void* d_out, int out_size, void* d_ws, size_t ws_size,
                              hipStream_t stream) {
    const float* x   = (const float*)d_in[0];
    const float* pos = (const float*)d_in[1];
    // d_in[2] = batch (int32) — layout is known (sorted, equal sized), unused
    const float* w1  = (const float*)d_in[3];
    const float* b1  = (const float*)d_in[4];
    const float* w2  = (const float*)d_in[5];
    const float* b2  = (const float*)d_in[6];
    const float* w3  = (const float*)d_in[7];
    const float* b3  = (const float*)d_in[8];

    float* out_x     = (float*)d_out;                       // [B*M,128]
    float* out_pos   = out_x + (size_t)BG * MC * 128;       // [B*M,3]
    float* out_batch = out_pos + (size_t)BG * MC * 3;       // [B*M] (written as float)

    char* ws   = (char*)d_ws;
    float* y   = (float*)ws;                    // 8 MB: [B*N,64] = x@W1x + b1
    int* cidx  = (int*)(ws + 8388608);          // 64 KB
    int* cntg  = (int*)(ws + 8454144);          // 64 KB
    int* nbr   = (int*)(ws + 8519680);          // 4 MB

    hipLaunchKernelGGL(k1_fps_y, dim3(8 + 512), dim3(256), 0, stream,
                       pos, x, w1, b1, y, cidx, out_pos, out_batch);
    hipLaunchKernelGGL(k2_nbr, dim3(256), dim3(256), 0, stream,
                       pos, cidx, nbr, cntg);
    hipLaunchKernelGGL(k3_mlp, dim3(1024), dim3(256), 0, stream,
                       y, pos, nbr, cntg, w1, w2, b2, w3, b3, out_pos, out_x);
}

// Round 3
// 1946.524 us; speedup vs baseline: 1.5682x; 1.5682x over previous
//
#include <hip/hip_runtime.h>

#define BG 8
#define NP 4096
#define MC 2048
#define KN 64

// Exact-rounding squared distance matching JAX/np f32 semantics:
// ((dx*dx + dy*dy) + dz*dz), no FMA contraction.
__device__ __forceinline__ float dist2(float ax, float ay, float az,
                                       float bx, float by, float bz) {
    float dx = __fsub_rn(ax, bx), dy = __fsub_rn(ay, by), dz = __fsub_rn(az, bz);
    return __fadd_rn(__fadd_rn(__fmul_rn(dx, dx), __fmul_rn(dy, dy)), __fmul_rn(dz, dz));
}

// f32 max reduce step via DPP (VALU-speed cross-lane). bound_ctrl=1 -> OOB
// lanes contribute 0, safe since operands are >= 0 (or -1 sentinel beaten by 0).
template <int CTRL>
__device__ __forceinline__ float dppmax(float v) {
    int t = __builtin_amdgcn_update_dpp(0, __float_as_int(v), CTRL, 0xf, 0xf, true);
    return fmaxf(v, __int_as_float(t));
}

// ---------------- Kernel 1: FPS (blocks 0..7) + y = x@W1x + b1 (blocks 8..263) -------------
__global__ __launch_bounds__(512) void k1_fps_y(
    const float* __restrict__ pos, const float* __restrict__ x,
    const float* __restrict__ w1, const float* __restrict__ b1,
    float* __restrict__ y, int* __restrict__ cidx,
    float* __restrict__ out_pos, float* __restrict__ out_batch)
{
    __shared__ float smem[12544];
    const int tid = threadIdx.x;
    if (blockIdx.x < BG) {
        // -------- FPS for graph b: 8 waves, 8 points/thread --------
        const int b = blockIdx.x;
        const float* pg = pos + (size_t)b * NP * 3;
        for (int i = tid; i < NP * 3; i += 512) smem[i] = pg[i];
        __syncthreads();
        const int lane = tid & 63, wv = tid >> 6;
        float px[8], py[8], pz[8], mind[8];
        const int base = tid * 8;
        #pragma unroll
        for (int i = 0; i < 8; i++) {
            px[i] = smem[(base + i) * 3];
            py[i] = smem[(base + i) * 3 + 1];
            pz[i] = smem[(base + i) * 3 + 2];
            mind[i] = 1e30f;
        }
        float2* sl = (float2*)(smem + NP * 3);   // 2 x 8 double-buffered (V, idx) slots
        float cx = smem[0], cy = smem[1], cz = smem[2];
        if (tid == 0) {
            cidx[b * MC] = 0;
            out_pos[(size_t)b * MC * 3 + 0] = cx;
            out_pos[(size_t)b * MC * 3 + 1] = cy;
            out_pos[(size_t)b * MC * 3 + 2] = cz;
            out_batch[b * MC] = (float)b;
        }
        for (int m = 1; m < MC; m++) {
            // update min distances; track thread-local (max, first idx)
            float bv = -1.0f; int bi = base;
            #pragma unroll
            for (int i = 0; i < 8; i++) {
                float d = dist2(px[i], py[i], pz[i], cx, cy, cz);
                float nm = fminf(mind[i], d);
                mind[i] = nm;
                if (nm > bv) { bv = nm; bi = base + i; }  // strict > keeps first idx
            }
            // wave max via DPP
            float v = bv;
            v = dppmax<0x111>(v);  // row_shr:1
            v = dppmax<0x112>(v);  // row_shr:2
            v = dppmax<0x114>(v);  // row_shr:4
            v = dppmax<0x118>(v);  // row_shr:8
            v = dppmax<0x142>(v);  // row_bcast:15
            v = dppmax<0x143>(v);  // row_bcast:31
            const float V = __int_as_float(__builtin_amdgcn_readlane(__float_as_int(v), 63));
            // first candidate lane = min index (lane order == index order)
            unsigned long long mk = __ballot(bv == V);
            float2* sb = sl + (m & 1) * 8;
            if (lane == (int)(__ffsll((long long)mk) - 1))
                sb[wv] = make_float2(V, __int_as_float(bi));
            __syncthreads();
            // every thread folds the 8 wave slots (ascending wave, strict >)
            const float4* sq = (const float4*)sb;
            float4 q0 = sq[0], q1 = sq[1], q2 = sq[2], q3 = sq[3];
            float Vg = q0.x; int ig = __float_as_int(q0.y);
            if (q0.z > Vg) { Vg = q0.z; ig = __float_as_int(q0.w); }
            if (q1.x > Vg) { Vg = q1.x; ig = __float_as_int(q1.y); }
            if (q1.z > Vg) { Vg = q1.z; ig = __float_as_int(q1.w); }
            if (q2.x > Vg) { Vg = q2.x; ig = __float_as_int(q2.y); }
            if (q2.z > Vg) { Vg = q2.z; ig = __float_as_int(q2.w); }
            if (q3.x > Vg) { Vg = q3.x; ig = __float_as_int(q3.y); }
            if (q3.z > Vg) { Vg = q3.z; ig = __float_as_int(q3.w); }
            cx = smem[ig * 3]; cy = smem[ig * 3 + 1]; cz = smem[ig * 3 + 2];
            if (tid == 0) {
                const int ci = b * MC + m;
                cidx[ci] = ig;
                out_pos[(size_t)ci * 3] = cx;
                out_pos[(size_t)ci * 3 + 1] = cy;
                out_pos[(size_t)ci * 3 + 2] = cz;
                out_batch[ci] = (float)b;
            }
        }
    } else {
        // -------- y = x @ W1x + b1 (128 points per block) --------
        const int q = blockIdx.x - BG;   // 0..255
        const int p0 = q * 128;
        float* xs = smem;                 // 128 x 65 (padded)
        float* wsm = smem + 8320;         // 64 x 64
        float* bsm = smem + 12416;        // 64
        for (int i = tid; i < 8192; i += 512)
            xs[(i >> 6) * 65 + (i & 63)] = x[(size_t)p0 * 64 + i];
        for (int i = tid; i < 4096; i += 512) wsm[i] = w1[i];
        if (tid < 64) bsm[tid] = b1[tid];
        __syncthreads();
        const int pl = tid >> 2, oq = tid & 3;
        float acc[16];
        #pragma unroll
        for (int u = 0; u < 16; u++) acc[u] = bsm[oq * 16 + u];
        for (int f = 0; f < 64; f++) {
            float xv = xs[pl * 65 + f];
            const float4* wp = (const float4*)&wsm[f * 64 + oq * 16];
            float4 a = wp[0], b4 = wp[1], c4 = wp[2], d4 = wp[3];
            acc[0] = fmaf(xv, a.x, acc[0]);   acc[1] = fmaf(xv, a.y, acc[1]);
            acc[2] = fmaf(xv, a.z, acc[2]);   acc[3] = fmaf(xv, a.w, acc[3]);
            acc[4] = fmaf(xv, b4.x, acc[4]);  acc[5] = fmaf(xv, b4.y, acc[5]);
            acc[6] = fmaf(xv, b4.z, acc[6]);  acc[7] = fmaf(xv, b4.w, acc[7]);
            acc[8] = fmaf(xv, c4.x, acc[8]);  acc[9] = fmaf(xv, c4.y, acc[9]);
            acc[10] = fmaf(xv, c4.z, acc[10]); acc[11] = fmaf(xv, c4.w, acc[11]);
            acc[12] = fmaf(xv, d4.x, acc[12]); acc[13] = fmaf(xv, d4.y, acc[13]);
            acc[14] = fmaf(xv, d4.z, acc[14]); acc[15] = fmaf(xv, d4.w, acc[15]);
        }
        float4* yo = (float4*)&y[((size_t)p0 + pl) * 64 + oq * 16];
        yo[0] = make_float4(acc[0], acc[1], acc[2], acc[3]);
        yo[1] = make_float4(acc[4], acc[5], acc[6], acc[7]);
        yo[2] = make_float4(acc[8], acc[9], acc[10], acc[11]);
        yo[3] = make_float4(acc[12], acc[13], acc[14], acc[15]);
    }
}

// ---------------- Kernel 2: radius-capped kNN per center -------------
__global__ __launch_bounds__(256) void k2_nbr(
    const float* __restrict__ pos, const int* __restrict__ cidx,
    int* __restrict__ nbr, int* __restrict__ cntg)
{
    __shared__ float smem[12288 + 4 * 480 * 2];
    const int tid = threadIdx.x, lane = tid & 63, wv = tid >> 6;
    const int b = blockIdx.x >> 5, blk = blockIdx.x & 31;
    const float* pg = pos + (size_t)b * NP * 3;
    for (int i = tid; i < NP * 3; i += 256) smem[i] = pg[i];
    __syncthreads();
    float2* cb = (float2*)(smem + 12288) + wv * 480;
    const int wi = blk * 4 + wv;    // 0..127
    for (int t = 0; t < 16; t++) {
        const int m = wi + 128 * t, ci = b * MC + m;
        const int cj = cidx[ci];
        const float cx = smem[cj * 3], cy = smem[cj * 3 + 1], cz = smem[cj * 3 + 2];
        int cnt = 0;
        for (int c = 0; c < 64; c++) {
            const int p = c * 64 + lane;
            float d2 = dist2(smem[p * 3], smem[p * 3 + 1], smem[p * 3 + 2], cx, cy, cz);
            bool inr = d2 <= 0.25f;
            unsigned long long mk = __ballot(inr);
            int pre = __popcll(mk & ((1ull << lane) - 1ull));
            int wp = cnt + pre;
            if (inr && wp < 480) cb[wp] = make_float2(d2, __int_as_float(p));
            cnt += __popcll(mk);
        }
        if (cnt > 480) cnt = 480;
        if (cnt <= KN) {
            if (lane < cnt) { float2 e = cb[lane]; nbr[(size_t)ci * KN + lane] = __float_as_int(e.y); }
            if (lane == 0) cntg[ci] = cnt;
        } else {
            for (int basej = 0; basej < cnt; basej += 64) {
                int jj = basej + lane;
                float dj = 3.4e38f; int ij = 0x7fffffff;
                bool act = jj < cnt;
                if (act) { float2 e = cb[jj]; dj = e.x; ij = __float_as_int(e.y); }
                int rank = 0;
                for (int l = 0; l < cnt; l++) {
                    float2 e = cb[l];
                    float dl = e.x; int il = __float_as_int(e.y);
                    if (dl < dj || (dl == dj && il < ij)) rank++;
                }
                if (act && rank < KN) nbr[(size_t)ci * KN + rank] = ij;
            }
            if (lane == 0) cntg[ci] = KN;
        }
    }
}

// ---------------- Kernel 3: per-center MLP + masked max -------------
__global__ __launch_bounds__(256, 2) void k3_mlp(
    const float* __restrict__ y, const float* __restrict__ pos,
    const int* __restrict__ nbr, const int* __restrict__ cntg,
    const float* __restrict__ w1, const float* __restrict__ w2, const float* __restrict__ b2,
    const float* __restrict__ w3, const float* __restrict__ b3,
    const float* __restrict__ out_pos, float* __restrict__ out_x)
{
    __shared__ float smem[4 * 136];
    const int tid = threadIdx.x, o = tid & 63, wv = tid >> 6;
    float w2c[64], w3a[64], w3b[64];
    #pragma unroll
    for (int f = 0; f < 64; f++) {
        w2c[f] = w2[f * 64 + o];
        w3a[f] = w3[f * 128 + o];
        w3b[f] = w3[f * 128 + 64 + o];
    }
    const float b2v = b2[o], b3av = b3[o], b3bv = b3[o + 64];
    const float wp0 = w1[64 * 64 + o], wp1 = w1[65 * 64 + o], wp2 = w1[66 * 64 + o];
    float* st1 = smem + wv * 136;
    float* st2 = st1 + 68;
    const int gw = blockIdx.x * 4 + wv;   // 0..4095
    for (int t = 0; t < 4; t++) {
        const int ci = gw + 4096 * t;
        const int b = ci >> 11;           // / MC
        const int kc = cntg[ci];
        const float cx = out_pos[(size_t)ci * 3], cy = out_pos[(size_t)ci * 3 + 1], cz = out_pos[(size_t)ci * 3 + 2];
        float mA = -3.4e38f, mB = -3.4e38f;
        for (int k = 0; k < kc; k++) {
            const int j = nbr[(size_t)ci * KN + k];
            const size_t pj = (size_t)b * NP + j;
            float yv = y[pj * 64 + o];
            float jx = pos[pj * 3], jy = pos[pj * 3 + 1], jz = pos[pj * 3 + 2];
            float rx = jx - cx, ry = jy - cy, rz = jz - cz;
            float h1 = fmaf(rx, wp0, yv);
            h1 = fmaf(ry, wp1, h1);
            h1 = fmaf(rz, wp2, h1);
            h1 = fmaxf(h1, 0.f);
            st1[o] = h1;
            float a2 = b2v;
            #pragma unroll
            for (int fc = 0; fc < 16; fc++) {
                float4 h = *(const float4*)&st1[fc * 4];
                a2 = fmaf(h.x, w2c[fc * 4], a2);
                a2 = fmaf(h.y, w2c[fc * 4 + 1], a2);
                a2 = fmaf(h.z, w2c[fc * 4 + 2], a2);
                a2 = fmaf(h.w, w2c[fc * 4 + 3], a2);
            }
            float h2 = fmaxf(a2, 0.f);
            st2[o] = h2;
            float a3 = b3av, a4 = b3bv;
            #pragma unroll
            for (int fc = 0; fc < 16; fc++) {
                float4 h = *(const float4*)&st2[fc * 4];
                a3 = fmaf(h.x, w3a[fc * 4], a3);
                a3 = fmaf(h.y, w3a[fc * 4 + 1], a3);
                a3 = fmaf(h.z, w3a[fc * 4 + 2], a3);
                a3 = fmaf(h.w, w3a[fc * 4 + 3], a3);
                a4 = fmaf(h.x, w3b[fc * 4], a4);
                a4 = fmaf(h.y, w3b[fc * 4 + 1], a4);
                a4 = fmaf(h.z, w3b[fc * 4 + 2], a4);
                a4 = fmaf(h.w, w3b[fc * 4 + 3], a4);
            }
            mA = fmaxf(mA, a3);
            mB = fmaxf(mB, a4);
        }
        out_x[(size_t)ci * 128 + o] = mA;
        out_x[(size_t)ci * 128 + 64 + o] = mB;
    }
}

extern "C" void kernel_launch(void* const* d_in, const int* in_sizes, int n_in,
                              void* d_out, int out_size, void* d_ws, size_t ws_size,
                              hipStream_t stream) {
    const float* x   = (const float*)d_in[0];
    const float* pos = (const float*)d_in[1];
    // d_in[2] = batch (int32) — layout is known (sorted, equal sized), unused
    const float* w1  = (const float*)d_in[3];
    const float* b1  = (const float*)d_in[4];
    const float* w2  = (const float*)d_in[5];
    const float* b2  = (const float*)d_in[6];
    const float* w3  = (const float*)d_in[7];
    const float* b3  = (const float*)d_in[8];

    float* out_x     = (float*)d_out;                       // [B*M,128]
    float* out_pos   = out_x + (size_t)BG * MC * 128;       // [B*M,3]
    float* out_batch = out_pos + (size_t)BG * MC * 3;       // [B*M] (written as float)

    char* ws   = (char*)d_ws;
    float* y   = (float*)ws;                    // 8 MB: [B*N,64] = x@W1x + b1
    int* cidx  = (int*)(ws + 8388608);          // 64 KB
    int* cntg  = (int*)(ws + 8454144);          // 64 KB
    int* nbr   = (int*)(ws + 8519680);          // 4 MB

    hipLaunchKernelGGL(k1_fps_y, dim3(8 + 256), dim3(512), 0, stream,
                       pos, x, w1, b1, y, cidx, out_pos, out_batch);
    hipLaunchKernelGGL(k2_nbr, dim3(256), dim3(256), 0, stream,
                       pos, cidx, nbr, cntg);
    hipLaunchKernelGGL(k3_mlp, dim3(1024), dim3(256), 0, stream,
                       y, pos, nbr, cntg, w1, w2, b2, w3, b3, out_pos, out_x);
}